// Round 8
// baseline (346.879 us; speedup 1.0000x reference)
//
#include <hip/hip_runtime.h>

// Problem constants
#define B_ 8
#define N_ 2000
#define D_ 480          // NH*C = 30*16
#define L_ 8
#define K_ 4096
#define T1_ 6

#define BM 64
#define BN 96

typedef __attribute__((ext_vector_type(4))) float f32x4;
typedef __attribute__((ext_vector_type(8))) short bf16x8;

__device__ __forceinline__ unsigned short f2bf(float f) {
    unsigned int u = __builtin_bit_cast(unsigned int, f);
    u += 0x7fffu + ((u >> 16) & 1u);   // RNE
    return (unsigned short)(u >> 16);
}
__device__ __forceinline__ float bf2f(unsigned short u) {
    return __builtin_bit_cast(float, ((unsigned int)u) << 16);
}

// ---------------------------------------------------------------------------
// is_end storage sniff: 1 => 1-byte bool, 0 => int32 (bytes %4!=0 all zero).
__global__ __launch_bounds__(256)
void k_flag(const unsigned char* __restrict__ raw, int* flag) {
    int t = threadIdx.x;
    if (t == 0) *flag = 0;
    __syncthreads();
    int any = 0;
    for (int i = t; i < 4096; i += 256) {
        if ((i & 3) != 0 && raw[i] != 0) any = 1;
    }
    if (__any(any) && (t & 63) == 0) atomicOr(flag, 1);
}

__global__ void k_wconv(const float* __restrict__ w,
                        unsigned short* __restrict__ wbf) {
    int i = blockIdx.x * blockDim.x + threadIdx.x;
    if (i < D_ * D_) wbf[i] = f2bf(w[i]);
}

__global__ void k_feats2bf(const float* __restrict__ f,
                           unsigned short* __restrict__ o) {
    int i = blockIdx.x * blockDim.x + threadIdx.x;   // over float4s
    if (i < B_ * N_ * D_ / 4) {
        float4 v = ((const float4*)f)[i];
        ushort4 u;
        u.x = f2bf(v.x); u.y = f2bf(v.y); u.z = f2bf(v.z); u.w = f2bf(v.w);
        ((ushort4*)o)[i] = u;
    }
}

__global__ void k_zero_idx(int* __restrict__ counts, int* __restrict__ cursor) {
    int i = blockIdx.x * blockDim.x + threadIdx.x;
    if (i < B_ * N_) { counts[i] = 0; cursor[i] = 0; }
}

__global__ void k_endcounts(const unsigned char* __restrict__ raw,
                            const int* __restrict__ flag,
                            const int* __restrict__ seg,
                            int* __restrict__ endi, int* __restrict__ counts) {
    int i = blockIdx.x * blockDim.x + threadIdx.x;
    if (i >= B_ * L_ * K_) return;
    int e = (*flag) ? (int)raw[i] : ((const int*)raw)[i];
    e = (e != 0) ? 1 : 0;
    endi[i] = e;
    if (e) {
        int b = i / (L_ * K_);
        atomicAdd(&counts[b * N_ + seg[i]], 1);
    }
}

// offsets = exclusive prefix sum of counts (B*N entries -> B*N+1 offsets)
__global__ __launch_bounds__(256)
void k_scan(const int* __restrict__ counts, int* __restrict__ offsets) {
    __shared__ int part[256];
    const int CH = 63;                       // 256*63 = 16128 >= 16000
    int t = threadIdx.x;
    int s = 0;
    for (int j = 0; j < CH; ++j) {
        int i = t * CH + j;
        if (i < B_ * N_) s += counts[i];
    }
    part[t] = s;
    __syncthreads();
    if (t == 0) {
        int run = 0;
        for (int i = 0; i < 256; ++i) { int v = part[i]; part[i] = run; run += v; }
    }
    __syncthreads();
    int run = part[t];
    for (int j = 0; j < CH; ++j) {
        int i = t * CH + j;
        if (i < B_ * N_) { offsets[i] = run; run += counts[i]; }
    }
    if (t == 255) offsets[B_ * N_] = run;
}

// nodelist grouped by (b,n): entry = l*K + k  (l<8, K=4096 -> (l<<12)|k)
__global__ void k_build(const int* __restrict__ endi,
                        const int* __restrict__ seg,
                        const int* __restrict__ offsets,
                        int* __restrict__ cursor, int* __restrict__ nodelist) {
    int i = blockIdx.x * blockDim.x + threadIdx.x;   // over B*L*K
    if (i >= B_ * L_ * K_) return;
    if (!endi[i]) return;
    int b = i / (L_ * K_);
    int lk = i - b * (L_ * K_);                      // l*K + k
    int n = seg[i];
    int pos = atomicAdd(&cursor[b * N_ + n], 1);
    nodelist[offsets[b * N_ + n] + pos] = lk;
}

// ---------------------------------------------------------------------------
// Level l>=1: pipelined LDS GEMM.  Z_l = diag(alpha)*(Z_{l-1}[gidx] @ W^T)+H_l
// Tile 128x160, BK=32, 512 threads = 8 waves (4M x 2N), wave = 32x80 = 2x5
// frags of 16x16x32 bf16 -> acc = 40 VGPR/thread (was 80: round-7's 4-wave
// version spilled at the 170-reg cap).  launch_bounds(512,4): cap 128 VGPR,
// no spill; 2 blocks/CU = 16 waves/CU.  A,B double-buffered in LDS (80B row
// stride), one barrier per K-step, loads for s+1 issued before s's MFMAs.
// Grid 768 = 8 batches x 32 M x 3 N; id&7 = batch -> batch slab per XCD L2.
__global__ __launch_bounds__(512, 4)
void k_level_gemm(const float* __restrict__ attn,
                  const int* __restrict__ seg, const int* __restrict__ parent,
                  const unsigned short* __restrict__ featsbf,
                  const unsigned short* __restrict__ wb,
                  const unsigned short* __restrict__ zprev,
                  unsigned short* __restrict__ zcur,
                  int l, int prevRows, int useps) {
    __shared__ unsigned short As[2][128 * 40];   // 80B/row stride
    __shared__ unsigned short Bs[2][160 * 40];
    __shared__ int gidx_s[128], seg_s[128];
    __shared__ float alpha_s[128];

    int tid = threadIdx.x;
    int id = blockIdx.x;                 // 768 = 8 xcds x 96
    int b = id & 7;                      // batch == XCD chunk
    int within = id >> 3;                // 0..95
    int mb = within / 3, nb = within - mb * 3;
    int k0 = mb * 128, d0 = nb * 160;

    if (tid < 128) {
        int base = (b * L_ + l) * K_;
        int p = parent[base + k0 + tid];
        int sk = seg[base + k0 + tid];
        int ps = seg[base - K_ + p];
        gidx_s[tid] = useps ? ps : p;
        seg_s[tid] = sk;
        alpha_s[tid] = attn[((size_t)b * N_ + ps) * N_ + sk];
    }
    __syncthreads();

    const unsigned short* zb = zprev + (size_t)b * prevRows * D_;

    // staging: 16B chunks. A: 128 rows x 4 = 512 = 1/thread.
    // B: 160 rows x 4 = 640 = 1/thread + extra for tid<128.
    int ar = tid >> 2, ao = (tid & 3) * 8;   // ao in shorts
    const unsigned short* asrc = zb + (size_t)gidx_s[ar] * D_ + ao;
    int aw = ar * 40 + ao;
    const unsigned short* bsrc0 = wb + (size_t)(d0 + ar) * D_ + ao;
    int bw0 = ar * 40 + ao;
    int br1 = 128 + (tid >> 2);
    const unsigned short* bsrc1 = wb + (size_t)(d0 + (br1 < 160 ? br1 : 159)) * D_ + ao;
    int bw1 = br1 * 40 + ao;
    bool hasB1 = (tid < 128);

    // fragment base offsets (shorts)
    int wave = tid >> 6, lane = tid & 63;
    int waveM = wave >> 1, waveN = wave & 1;  // 4M x 2N
    int lr = lane & 15, kg = lane >> 4;
    int afb[2], bfb[5];
#pragma unroll
    for (int fm = 0; fm < 2; ++fm)
        afb[fm] = (waveM * 32 + fm * 16 + lr) * 40 + kg * 8;
#pragma unroll
    for (int fn = 0; fn < 5; ++fn)
        bfb[fn] = (waveN * 80 + fn * 16 + lr) * 40 + kg * 8;

    f32x4 acc[2][5];
#pragma unroll
    for (int fm = 0; fm < 2; ++fm)
#pragma unroll
        for (int fn = 0; fn < 5; ++fn) acc[fm][fn] = (f32x4)0.f;

    // prologue: stage step 0 into buf 0
    {
        f32x4 ra = *(const f32x4*)asrc;
        f32x4 rb0 = *(const f32x4*)bsrc0;
        f32x4 rb1;
        if (hasB1) rb1 = *(const f32x4*)bsrc1;
        *(f32x4*)&As[0][aw] = ra;
        *(f32x4*)&Bs[0][bw0] = rb0;
        if (hasB1) *(f32x4*)&Bs[0][bw1] = rb1;
    }
    __syncthreads();

    for (int s = 0; s < 15; ++s) {
        int cur = s & 1;
        f32x4 ra, rb0, rb1;
        if (s < 14) {                      // issue next-step loads early
            int off = (s + 1) * 32;
            ra = *(const f32x4*)(asrc + off);
            rb0 = *(const f32x4*)(bsrc0 + off);
            if (hasB1) rb1 = *(const f32x4*)(bsrc1 + off);
        }
        bf16x8 af[2], bfr[5];
#pragma unroll
        for (int fm = 0; fm < 2; ++fm)
            af[fm] = *(const bf16x8*)&As[cur][afb[fm]];
#pragma unroll
        for (int fn = 0; fn < 5; ++fn)
            bfr[fn] = *(const bf16x8*)&Bs[cur][bfb[fn]];
#pragma unroll
        for (int fm = 0; fm < 2; ++fm)
#pragma unroll
            for (int fn = 0; fn < 5; ++fn)
                acc[fm][fn] = __builtin_amdgcn_mfma_f32_16x16x32_bf16(
                    af[fm], bfr[fn], acc[fm][fn], 0, 0, 0);
        if (s < 14) {                      // write-late into other buffer
            *(f32x4*)&As[cur ^ 1][aw] = ra;
            *(f32x4*)&Bs[cur ^ 1][bw0] = rb0;
            if (hasB1) *(f32x4*)&Bs[cur ^ 1][bw1] = rb1;
        }
        __syncthreads();
    }

    // epilogue: C layout col=lane&15, row=(lane>>4)*4+j
#pragma unroll
    for (int fm = 0; fm < 2; ++fm) {
#pragma unroll
        for (int j = 0; j < 4; ++j) {
            int rl = waveM * 32 + fm * 16 + kg * 4 + j;
            float al = alpha_s[rl];
            int sk = seg_s[rl];
            const unsigned short* hrow = featsbf + ((size_t)b * N_ + sk) * D_;
            unsigned short* zrow = zcur + ((size_t)b * K_ + k0 + rl) * D_;
#pragma unroll
            for (int fn = 0; fn < 5; ++fn) {
                int c = d0 + waveN * 80 + fn * 16 + lr;
                zrow[c] = f2bf(al * acc[fm][fn][j] + bf2f(hrow[c]));
            }
        }
    }
}

// Fused gather-reduce + mean + predictor + mask. One wave per (b,n).
__global__ __launch_bounds__(64)
void k_final_gather(const unsigned short* __restrict__ featsbf,
                    const unsigned short* __restrict__ zall,
                    const int* __restrict__ offsets,
                    const int* __restrict__ nodelist,
                    const float* __restrict__ Wpred,
                    const float* __restrict__ bpred, float* __restrict__ out) {
    int bn = blockIdx.x;
    int b = bn / N_;
    int s0 = offsets[bn], s1 = offsets[bn + 1];
    int cnt = s1 - s0;
    int lane = threadIdx.x;

    float acc[2][4] = {{0, 0, 0, 0}, {0, 0, 0, 0}};
    const unsigned short* ownrow = featsbf + (size_t)bn * D_;

    for (int s = s0; s < s1; ++s) {
        int e = nodelist[s];
        int l = e >> 12, k = e & (K_ - 1);
        const unsigned short* row =
            (l == 0) ? ownrow
                     : zall + (((size_t)(l - 1) * B_ + b) * K_ + k) * D_;
#pragma unroll
        for (int it = 0; it < 2; ++it) {
            int c4 = lane + 64 * it;
            if (c4 < D_ / 4) {
                ushort4 u = *(const ushort4*)(row + c4 * 4);
                acc[it][0] += bf2f(u.x);
                acc[it][1] += bf2f(u.y);
                acc[it][2] += bf2f(u.z);
                acc[it][3] += bf2f(u.w);
            }
        }
    }

    float inv = 1.f / (float)(cnt > 1 ? cnt : 1);
    float m[2][4];
#pragma unroll
    for (int it = 0; it < 2; ++it)
#pragma unroll
        for (int j = 0; j < 4; ++j) m[it][j] = acc[it][j] * inv;

    float* outz = out + (size_t)B_ * N_ * T1_ + (size_t)bn * D_;
#pragma unroll
    for (int it = 0; it < 2; ++it) {
        int c4 = lane + 64 * it;
        if (c4 < D_ / 4) {
            float4 v;
            v.x = m[it][0]; v.y = m[it][1]; v.z = m[it][2]; v.w = m[it][3];
            *(float4*)(outz + c4 * 4) = v;
        }
    }

    float part[T1_] = {0, 0, 0, 0, 0, 0};
#pragma unroll
    for (int it = 0; it < 2; ++it) {
        int c4 = lane + 64 * it;
        if (c4 < D_ / 4) {
#pragma unroll
            for (int t = 0; t < T1_; ++t)
#pragma unroll
                for (int j = 0; j < 4; ++j)
                    part[t] += m[it][j] * Wpred[t * D_ + c4 * 4 + j];
        }
    }
#pragma unroll
    for (int t = 0; t < T1_; ++t) {
        float v = part[t];
        for (int off = 32; off; off >>= 1) v += __shfl_down(v, off);
        if (lane == 0)
            out[(size_t)bn * T1_ + t] = (cnt > 0) ? (v + bpred[t]) : 0.f;
    }
    if (lane == 0)
        out[(size_t)B_ * N_ * T1_ + (size_t)B_ * N_ * D_ + bn] =
            (cnt > 0) ? 1.f : 0.f;
}

// ======================= fallback (atomic) path kernels =====================
__global__ void k_zero(float* __restrict__ sums, int* __restrict__ counts) {
    int stride = gridDim.x * blockDim.x;
    int i0 = blockIdx.x * blockDim.x + threadIdx.x;
    for (int i = i0; i < B_ * N_ * D_; i += stride) sums[i] = 0.f;
    for (int i = i0; i < B_ * N_; i += stride) counts[i] = 0;
}

__global__ __launch_bounds__(128)
void k_level0_at(const float* __restrict__ feats, const int* __restrict__ seg,
                 const int* __restrict__ endi, unsigned short* __restrict__ z0,
                 float* __restrict__ sums) {
    int bk = blockIdx.x;
    int b = bk >> 12;
    int k = bk & (K_ - 1);
    int sidx = (b * L_ + 0) * K_ + k;
    int n = seg[sidx];
    int e = endi[sidx];
    const float* src = feats + ((size_t)b * N_ + n) * D_;
    unsigned short* dst = z0 + ((size_t)b * K_ + k) * D_;
    float* sm = sums + ((size_t)b * N_ + n) * D_;
    int t = threadIdx.x;
    if (t < D_ / 4) {
        float4 v = *(const float4*)(src + t * 4);
        ushort4 o;
        o.x = f2bf(v.x); o.y = f2bf(v.y); o.z = f2bf(v.z); o.w = f2bf(v.w);
        *(ushort4*)(dst + t * 4) = o;
        if (e) {
            atomicAdd(&sm[t * 4 + 0], v.x);
            atomicAdd(&sm[t * 4 + 1], v.y);
            atomicAdd(&sm[t * 4 + 2], v.z);
            atomicAdd(&sm[t * 4 + 3], v.w);
        }
    }
}

__global__ __launch_bounds__(256)
void k_level_mfma_at(const float* __restrict__ feats,
                     const float* __restrict__ attn,
                     const int* __restrict__ seg, const int* __restrict__ parent,
                     const int* __restrict__ endi,
                     const unsigned short* __restrict__ wb,
                     const unsigned short* __restrict__ zprev,
                     unsigned short* __restrict__ zcur,
                     float* __restrict__ sums, int l, int storez) {
    __shared__ int par_s[BM], seg_s[BM], end_s[BM];
    __shared__ float alpha_s[BM];
    int b = blockIdx.z;
    int k0 = blockIdx.x * BM;
    int d0 = blockIdx.y * BN;
    int tid = threadIdx.x;
    if (tid < BM) {
        int base = (b * L_ + l) * K_;
        int p = parent[base + k0 + tid];
        int sk = seg[base + k0 + tid];
        int ps = seg[base - K_ + p];
        par_s[tid] = p; seg_s[tid] = sk;
        end_s[tid] = endi[base + k0 + tid];
        alpha_s[tid] = attn[((size_t)b * N_ + ps) * N_ + sk];
    }
    __syncthreads();
    int wave = tid >> 6, lane = tid & 63;
    int wr0 = (wave >> 1) * 32, wc0 = (wave & 1) * 48;
    int laneRow = lane & 15, laneK = (lane >> 4) * 8;
    const unsigned short* zb = zprev + (size_t)b * K_ * D_;
    const unsigned short* arow[2];
#pragma unroll
    for (int mi = 0; mi < 2; ++mi)
        arow[mi] = zb + (size_t)par_s[wr0 + mi * 16 + laneRow] * D_ + laneK;
    const unsigned short* brow[3];
#pragma unroll
    for (int ni = 0; ni < 3; ++ni)
        brow[ni] = wb + (size_t)(d0 + wc0 + ni * 16 + laneRow) * D_ + laneK;
    f32x4 acc[2][3];
#pragma unroll
    for (int mi = 0; mi < 2; ++mi)
#pragma unroll
        for (int ni = 0; ni < 3; ++ni) acc[mi][ni] = (f32x4)0.f;
    bf16x8 af[2], bfr[3];
#pragma unroll
    for (int mi = 0; mi < 2; ++mi) af[mi] = *(const bf16x8*)(arow[mi]);
#pragma unroll
    for (int ni = 0; ni < 3; ++ni) bfr[ni] = *(const bf16x8*)(brow[ni]);
#pragma unroll
    for (int e0 = 0; e0 < D_; e0 += 32) {
        bf16x8 an[2], bn[3];
        if (e0 + 32 < D_) {
#pragma unroll
            for (int mi = 0; mi < 2; ++mi) an[mi] = *(const bf16x8*)(arow[mi] + e0 + 32);
#pragma unroll
            for (int ni = 0; ni < 3; ++ni) bn[ni] = *(const bf16x8*)(brow[ni] + e0 + 32);
        }
#pragma unroll
        for (int mi = 0; mi < 2; ++mi)
#pragma unroll
            for (int ni = 0; ni < 3; ++ni)
                acc[mi][ni] = __builtin_amdgcn_mfma_f32_16x16x32_bf16(
                    af[mi], bfr[ni], acc[mi][ni], 0, 0, 0);
        if (e0 + 32 < D_) {
#pragma unroll
            for (int mi = 0; mi < 2; ++mi) af[mi] = an[mi];
#pragma unroll
            for (int ni = 0; ni < 3; ++ni) bfr[ni] = bn[ni];
        }
    }
#pragma unroll
    for (int mi = 0; mi < 2; ++mi) {
#pragma unroll
        for (int j = 0; j < 4; ++j) {
            int rl = wr0 + mi * 16 + (lane >> 4) * 4 + j;
            int k = k0 + rl;
            float al = alpha_s[rl];
            int sk = seg_s[rl];
            int en = end_s[rl];
            const float* hrow = feats + ((size_t)b * N_ + sk) * D_;
            unsigned short* zrow = zcur + ((size_t)b * K_ + k) * D_;
            float* srow = sums + ((size_t)b * N_ + sk) * D_;
#pragma unroll
            for (int ni = 0; ni < 3; ++ni) {
                int c = d0 + wc0 + ni * 16 + (lane & 15);
                float v = al * acc[mi][ni][j] + hrow[c];
                if (storez) zrow[c] = f2bf(v);
                if (en) atomicAdd(&srow[c], v);
            }
        }
    }
}

__global__ __launch_bounds__(64)
void k_final_at(const float* __restrict__ sums, const int* __restrict__ counts,
                const float* __restrict__ Wpred, const float* __restrict__ bpred,
                float* __restrict__ out) {
    int bn = blockIdx.x;
    int cnt = counts[bn];
    float inv = 1.f / (float)(cnt > 1 ? cnt : 1);
    int lane = threadIdx.x;
    const float* srow = sums + (size_t)bn * D_;
    float* zout = out + (size_t)B_ * N_ * T1_ + (size_t)bn * D_;
    float part[T1_] = {0, 0, 0, 0, 0, 0};
    for (int d = lane; d < D_; d += 64) {
        float mval = srow[d] * inv;
        zout[d] = mval;
#pragma unroll
        for (int t = 0; t < T1_; ++t) part[t] += mval * Wpred[t * D_ + d];
    }
#pragma unroll
    for (int t = 0; t < T1_; ++t) {
        float v = part[t];
        for (int off = 32; off; off >>= 1) v += __shfl_down(v, off);
        if (lane == 0)
            out[(size_t)bn * T1_ + t] = (cnt > 0) ? (v + bpred[t]) : 0.f;
    }
    if (lane == 0)
        out[(size_t)B_ * N_ * T1_ + (size_t)B_ * N_ * D_ + bn] =
            (cnt > 0) ? 1.f : 0.f;
}

// ===========================================================================
extern "C" void kernel_launch(void* const* d_in, const int* in_sizes, int n_in,
                              void* d_out, int out_size, void* d_ws,
                              size_t ws_size, hipStream_t stream) {
    const float* feats = (const float*)d_in[0];
    const float* attn  = (const float*)d_in[1];
    const int*   seg   = (const int*)d_in[2];
    const int*   par   = (const int*)d_in[3];
    const unsigned char* isend_raw = (const unsigned char*)d_in[4];
    const float* Wproj = (const float*)d_in[5];
    const float* Wpred = (const float*)d_in[6];
    const float* bpred = (const float*)d_in[7];

    char* p = (char*)d_ws;
    auto carve = [&p](size_t bytes) -> char* {
        char* r = p;
        p += (bytes + 255) & ~(size_t)255;
        return r;
    };

    // gather-path workspace
    size_t need = 0;
    {
        size_t q = 0;
        auto sz = [&q](size_t b) { q += (b + 255) & ~(size_t)255; };
        sz(B_ * N_ * 4);                    // counts
        sz(B_ * N_ * 4);                    // cursor
        sz((B_ * N_ + 1) * 4);              // offsets
        sz((size_t)B_ * L_ * K_ * 4);       // endi
        sz(16);                             // flag
        sz((size_t)B_ * L_ * K_ * 4);       // nodelist (worst case all end)
        sz((size_t)B_ * N_ * D_ * 2);       // featsbf
        sz((size_t)D_ * D_ * 2);            // wbf
        sz((size_t)(L_ - 1) * B_ * K_ * D_ * 2);  // zall: 7 slabs
        need = q;
    }

    if (ws_size >= need) {
        int* counts = (int*)carve(B_ * N_ * 4);
        int* cursor = (int*)carve(B_ * N_ * 4);
        int* offsets = (int*)carve((B_ * N_ + 1) * 4);
        int* endi = (int*)carve((size_t)B_ * L_ * K_ * 4);
        int* flag = (int*)carve(16);
        int* nodelist = (int*)carve((size_t)B_ * L_ * K_ * 4);
        unsigned short* featsbf = (unsigned short*)carve((size_t)B_ * N_ * D_ * 2);
        unsigned short* wbf = (unsigned short*)carve((size_t)D_ * D_ * 2);
        unsigned short* zall =
            (unsigned short*)carve((size_t)(L_ - 1) * B_ * K_ * D_ * 2);

        k_flag<<<1, 256, 0, stream>>>(isend_raw, flag);
        k_zero_idx<<<(B_ * N_ + 255) / 256, 256, 0, stream>>>(counts, cursor);
        k_wconv<<<(D_ * D_ + 255) / 256, 256, 0, stream>>>(Wproj, wbf);
        k_feats2bf<<<(B_ * N_ * D_ / 4 + 255) / 256, 256, 0, stream>>>(feats,
                                                                       featsbf);
        k_endcounts<<<(B_ * L_ * K_ + 255) / 256, 256, 0, stream>>>(
            isend_raw, flag, seg, endi, counts);
        k_scan<<<1, 256, 0, stream>>>(counts, offsets);
        k_build<<<(B_ * L_ * K_ + 255) / 256, 256, 0, stream>>>(
            endi, seg, offsets, cursor, nodelist);

        for (int l = 1; l < L_; ++l) {
            const unsigned short* zp =
                (l == 1) ? featsbf : zall + (size_t)(l - 2) * B_ * K_ * D_;
            unsigned short* zc = zall + (size_t)(l - 1) * B_ * K_ * D_;
            k_level_gemm<<<768, 512, 0, stream>>>(
                attn, seg, par, featsbf, wbf, zp, zc, l,
                (l == 1) ? N_ : K_, (l == 1) ? 1 : 0);
        }

        k_final_gather<<<B_ * N_, 64, 0, stream>>>(
            featsbf, zall, offsets, nodelist, Wpred, bpred, (float*)d_out);
    } else {
        // fallback: round-3 atomic path
        float* sums = (float*)carve((size_t)B_ * N_ * D_ * 4);
        int* counts = (int*)carve(B_ * N_ * 4);
        int* endi = (int*)carve((size_t)B_ * L_ * K_ * 4);
        int* flag = (int*)carve(16);
        unsigned short* z0bf = (unsigned short*)carve((size_t)B_ * K_ * D_ * 2);
        unsigned short* z1bf = (unsigned short*)carve((size_t)B_ * K_ * D_ * 2);
        unsigned short* wbf = (unsigned short*)carve((size_t)D_ * D_ * 2);

        k_flag<<<1, 256, 0, stream>>>(isend_raw, flag);
        k_zero<<<1024, 256, 0, stream>>>(sums, counts);
        k_wconv<<<(D_ * D_ + 255) / 256, 256, 0, stream>>>(Wproj, wbf);
        k_endcounts<<<(B_ * L_ * K_ + 255) / 256, 256, 0, stream>>>(
            isend_raw, flag, seg, endi, counts);
        k_level0_at<<<B_ * K_, 128, 0, stream>>>(feats, seg, endi, z0bf, sums);
        unsigned short* zp = z0bf;
        unsigned short* zc = z1bf;
        for (int l = 1; l < L_; ++l) {
            k_level_mfma_at<<<dim3(K_ / BM, D_ / BN, B_), 256, 0, stream>>>(
                feats, attn, seg, par, endi, wbf, zp, zc, sums, l,
                (l < L_ - 1) ? 1 : 0);
            unsigned short* t = zp; zp = zc; zc = t;
        }
        k_final_at<<<B_ * N_, 64, 0, stream>>>(sums, counts, Wpred, bpred,
                                               (float*)d_out);
    }
}

// Round 9
// 326.668 us; speedup vs baseline: 1.0619x; 1.0619x over previous
//
#include <hip/hip_runtime.h>

// Problem constants
#define B_ 8
#define N_ 2000
#define D_ 480          // NH*C = 30*16
#define L_ 8
#define K_ 4096
#define T1_ 6

#define BM 64
#define BN 96

typedef __attribute__((ext_vector_type(4))) float f32x4;
typedef __attribute__((ext_vector_type(8))) short bf16x8;

__device__ __forceinline__ unsigned short f2bf(float f) {
    unsigned int u = __builtin_bit_cast(unsigned int, f);
    u += 0x7fffu + ((u >> 16) & 1u);   // RNE
    return (unsigned short)(u >> 16);
}
__device__ __forceinline__ float bf2f(unsigned short u) {
    return __builtin_bit_cast(float, ((unsigned int)u) << 16);
}

// ---------------------------------------------------------------------------
// is_end storage sniff: 1 => 1-byte bool, 0 => int32 (bytes %4!=0 all zero).
__global__ __launch_bounds__(256)
void k_flag(const unsigned char* __restrict__ raw, int* flag) {
    int t = threadIdx.x;
    if (t == 0) *flag = 0;
    __syncthreads();
    int any = 0;
    for (int i = t; i < 4096; i += 256) {
        if ((i & 3) != 0 && raw[i] != 0) any = 1;
    }
    if (__any(any) && (t & 63) == 0) atomicOr(flag, 1);
}

__global__ void k_wconv(const float* __restrict__ w,
                        unsigned short* __restrict__ wbf) {
    int i = blockIdx.x * blockDim.x + threadIdx.x;
    if (i < D_ * D_) wbf[i] = f2bf(w[i]);
}

__global__ void k_feats2bf(const float* __restrict__ f,
                           unsigned short* __restrict__ o) {
    int i = blockIdx.x * blockDim.x + threadIdx.x;   // over float4s
    if (i < B_ * N_ * D_ / 4) {
        float4 v = ((const float4*)f)[i];
        ushort4 u;
        u.x = f2bf(v.x); u.y = f2bf(v.y); u.z = f2bf(v.z); u.w = f2bf(v.w);
        ((ushort4*)o)[i] = u;
    }
}

__global__ void k_zero_idx(int* __restrict__ counts, int* __restrict__ cursor) {
    int i = blockIdx.x * blockDim.x + threadIdx.x;
    if (i < B_ * N_) { counts[i] = 0; cursor[i] = 0; }
}

__global__ void k_endcounts(const unsigned char* __restrict__ raw,
                            const int* __restrict__ flag,
                            const int* __restrict__ seg,
                            int* __restrict__ endi, int* __restrict__ counts) {
    int i = blockIdx.x * blockDim.x + threadIdx.x;
    if (i >= B_ * L_ * K_) return;
    int e = (*flag) ? (int)raw[i] : ((const int*)raw)[i];
    e = (e != 0) ? 1 : 0;
    endi[i] = e;
    if (e) {
        int b = i / (L_ * K_);
        atomicAdd(&counts[b * N_ + seg[i]], 1);
    }
}

// offsets = exclusive prefix sum of counts (B*N entries -> B*N+1 offsets)
__global__ __launch_bounds__(256)
void k_scan(const int* __restrict__ counts, int* __restrict__ offsets) {
    __shared__ int part[256];
    const int CH = 63;                       // 256*63 = 16128 >= 16000
    int t = threadIdx.x;
    int s = 0;
    for (int j = 0; j < CH; ++j) {
        int i = t * CH + j;
        if (i < B_ * N_) s += counts[i];
    }
    part[t] = s;
    __syncthreads();
    if (t == 0) {
        int run = 0;
        for (int i = 0; i < 256; ++i) { int v = part[i]; part[i] = run; run += v; }
    }
    __syncthreads();
    int run = part[t];
    for (int j = 0; j < CH; ++j) {
        int i = t * CH + j;
        if (i < B_ * N_) { offsets[i] = run; run += counts[i]; }
    }
    if (t == 255) offsets[B_ * N_] = run;
}

// nodelist grouped by (b,n): entry = l*K + k  (l<8, K=4096 -> (l<<12)|k)
__global__ void k_build(const int* __restrict__ endi,
                        const int* __restrict__ seg,
                        const int* __restrict__ offsets,
                        int* __restrict__ cursor, int* __restrict__ nodelist) {
    int i = blockIdx.x * blockDim.x + threadIdx.x;   // over B*L*K
    if (i >= B_ * L_ * K_) return;
    if (!endi[i]) return;
    int b = i / (L_ * K_);
    int lk = i - b * (L_ * K_);                      // l*K + k
    int n = seg[i];
    int pos = atomicAdd(&cursor[b * N_ + n], 1);
    nodelist[offsets[b * N_ + n] + pos] = lk;
}

// ---------------------------------------------------------------------------
// Level l>=1: depth-2 pipelined LDS GEMM (triple-buffered).
// Z_l = diag(alpha)*(Z_{l-1}[gidx] @ W^T) + H_l.
// Tile 128x160, BK=32, 512 threads = 8 waves (4M x 2N), wave = 32x80 = 2x5
// frags of 16x16x32 bf16.  Slice s+2's global loads are issued at step s and
// LDS-written at step s+1 -> ~2 full steps of latency cover (r8's depth-1
// exposed one L2/L3 gather latency per barrier -> both pipes idle).
// Grid 768 = 8 batches x 32 M x 3 N; id&7 = batch -> batch slab per XCD L2.
__global__ __launch_bounds__(512, 4)
void k_level_gemm(const float* __restrict__ attn,
                  const int* __restrict__ seg, const int* __restrict__ parent,
                  const unsigned short* __restrict__ featsbf,
                  const unsigned short* __restrict__ wb,
                  const unsigned short* __restrict__ zprev,
                  unsigned short* __restrict__ zcur,
                  int l, int prevRows, int useps) {
    __shared__ unsigned short As[3][128 * 40];   // 80B/row stride
    __shared__ unsigned short Bs[3][160 * 40];
    __shared__ int gidx_s[128], seg_s[128];
    __shared__ float alpha_s[128];

    int tid = threadIdx.x;
    int id = blockIdx.x;                 // 768 = 8 xcds x 96
    int b = id & 7;                      // batch == XCD chunk
    int within = id >> 3;                // 0..95
    int mb = within / 3, nb = within - mb * 3;
    int k0 = mb * 128, d0 = nb * 160;

    if (tid < 128) {
        int base = (b * L_ + l) * K_;
        int p = parent[base + k0 + tid];
        int sk = seg[base + k0 + tid];
        int ps = seg[base - K_ + p];
        gidx_s[tid] = useps ? ps : p;
        seg_s[tid] = sk;
        alpha_s[tid] = attn[((size_t)b * N_ + ps) * N_ + sk];
    }
    __syncthreads();

    const unsigned short* zb = zprev + (size_t)b * prevRows * D_;

    // staging: 16B chunks. A: 128 rows x 4 = 512 = 1/thread.
    // B: 160 rows x 4 = 640 = 1/thread + extra for tid<128.
    int ar = tid >> 2, ao = (tid & 3) * 8;   // ao in shorts
    const unsigned short* asrc = zb + (size_t)gidx_s[ar] * D_ + ao;
    int aw = ar * 40 + ao;
    const unsigned short* bsrc0 = wb + (size_t)(d0 + ar) * D_ + ao;
    int bw0 = ar * 40 + ao;
    int br1 = 128 + (tid >> 2);
    const unsigned short* bsrc1 = wb + (size_t)(d0 + (br1 < 160 ? br1 : 159)) * D_ + ao;
    int bw1 = br1 * 40 + ao;
    bool hasB1 = (tid < 128);

    // fragment base offsets (shorts)
    int wave = tid >> 6, lane = tid & 63;
    int waveM = wave >> 1, waveN = wave & 1;  // 4M x 2N
    int lr = lane & 15, kg = lane >> 4;
    int afb[2], bfb[5];
#pragma unroll
    for (int fm = 0; fm < 2; ++fm)
        afb[fm] = (waveM * 32 + fm * 16 + lr) * 40 + kg * 8;
#pragma unroll
    for (int fn = 0; fn < 5; ++fn)
        bfb[fn] = (waveN * 80 + fn * 16 + lr) * 40 + kg * 8;

    f32x4 acc[2][5];
#pragma unroll
    for (int fm = 0; fm < 2; ++fm)
#pragma unroll
        for (int fn = 0; fn < 5; ++fn) acc[fm][fn] = (f32x4)0.f;

    // 2-deep staging registers: slot = slice & 1
    f32x4 ra[2], rb0[2], rb1[2];

    // prologue: slices 0,1 -> LDS[0],LDS[1]; slice 2 -> reg slot 0
    {
        f32x4 a0 = *(const f32x4*)(asrc);
        f32x4 b00 = *(const f32x4*)(bsrc0);
        f32x4 b10; if (hasB1) b10 = *(const f32x4*)(bsrc1);
        f32x4 a1 = *(const f32x4*)(asrc + 32);
        f32x4 b01 = *(const f32x4*)(bsrc0 + 32);
        f32x4 b11; if (hasB1) b11 = *(const f32x4*)(bsrc1 + 32);
        ra[0]  = *(const f32x4*)(asrc + 64);
        rb0[0] = *(const f32x4*)(bsrc0 + 64);
        if (hasB1) rb1[0] = *(const f32x4*)(bsrc1 + 64);
        *(f32x4*)&As[0][aw] = a0;
        *(f32x4*)&Bs[0][bw0] = b00;
        if (hasB1) *(f32x4*)&Bs[0][bw1] = b10;
        *(f32x4*)&As[1][aw] = a1;
        *(f32x4*)&Bs[1][bw0] = b01;
        if (hasB1) *(f32x4*)&Bs[1][bw1] = b11;
    }
    __syncthreads();

#pragma unroll
    for (int s = 0; s < 15; ++s) {
        // phase 1: issue slice s+2 (slices 0..2 already issued in prologue)
        if (s >= 1 && s + 2 <= 14) {
            int off = (s + 2) * 32;
            int sl = s & 1;                    // (s+2)&1 == s&1
            ra[sl] = *(const f32x4*)(asrc + off);
            rb0[sl] = *(const f32x4*)(bsrc0 + off);
            if (hasB1) rb1[sl] = *(const f32x4*)(bsrc1 + off);
        }
        // phase 2: fragments + MFMA from buffer s%3
        int cur = s % 3;
        bf16x8 af[2], bfr[5];
#pragma unroll
        for (int fm = 0; fm < 2; ++fm)
            af[fm] = *(const bf16x8*)&As[cur][afb[fm]];
#pragma unroll
        for (int fn = 0; fn < 5; ++fn)
            bfr[fn] = *(const bf16x8*)&Bs[cur][bfb[fn]];
#pragma unroll
        for (int fm = 0; fm < 2; ++fm)
#pragma unroll
            for (int fn = 0; fn < 5; ++fn)
                acc[fm][fn] = __builtin_amdgcn_mfma_f32_16x16x32_bf16(
                    af[fm], bfr[fn], acc[fm][fn], 0, 0, 0);
        // phase 3: write slice s+1 (issued at step s-1) into buffer (s+1)%3
        if (s <= 13) {
            int sl = (s + 1) & 1;
            int buf = (s + 1) % 3;
            *(f32x4*)&As[buf][aw] = ra[sl];
            *(f32x4*)&Bs[buf][bw0] = rb0[sl];
            if (hasB1) *(f32x4*)&Bs[buf][bw1] = rb1[sl];
        }
        __syncthreads();
    }

    // epilogue: C layout col=lane&15, row=(lane>>4)*4+j
#pragma unroll
    for (int fm = 0; fm < 2; ++fm) {
#pragma unroll
        for (int j = 0; j < 4; ++j) {
            int rl = waveM * 32 + fm * 16 + kg * 4 + j;
            float al = alpha_s[rl];
            int sk = seg_s[rl];
            const unsigned short* hrow = featsbf + ((size_t)b * N_ + sk) * D_;
            unsigned short* zrow = zcur + ((size_t)b * K_ + k0 + rl) * D_;
#pragma unroll
            for (int fn = 0; fn < 5; ++fn) {
                int c = d0 + waveN * 80 + fn * 16 + lr;
                zrow[c] = f2bf(al * acc[fm][fn][j] + bf2f(hrow[c]));
            }
        }
    }
}

// Fused gather-reduce + mean + predictor + mask. One wave per (b,n).
__global__ __launch_bounds__(64)
void k_final_gather(const unsigned short* __restrict__ featsbf,
                    const unsigned short* __restrict__ zall,
                    const int* __restrict__ offsets,
                    const int* __restrict__ nodelist,
                    const float* __restrict__ Wpred,
                    const float* __restrict__ bpred, float* __restrict__ out) {
    int bn = blockIdx.x;
    int b = bn / N_;
    int s0 = offsets[bn], s1 = offsets[bn + 1];
    int cnt = s1 - s0;
    int lane = threadIdx.x;

    float acc[2][4] = {{0, 0, 0, 0}, {0, 0, 0, 0}};
    const unsigned short* ownrow = featsbf + (size_t)bn * D_;

    for (int s = s0; s < s1; ++s) {
        int e = nodelist[s];
        int l = e >> 12, k = e & (K_ - 1);
        const unsigned short* row =
            (l == 0) ? ownrow
                     : zall + (((size_t)(l - 1) * B_ + b) * K_ + k) * D_;
#pragma unroll
        for (int it = 0; it < 2; ++it) {
            int c4 = lane + 64 * it;
            if (c4 < D_ / 4) {
                ushort4 u = *(const ushort4*)(row + c4 * 4);
                acc[it][0] += bf2f(u.x);
                acc[it][1] += bf2f(u.y);
                acc[it][2] += bf2f(u.z);
                acc[it][3] += bf2f(u.w);
            }
        }
    }

    float inv = 1.f / (float)(cnt > 1 ? cnt : 1);
    float m[2][4];
#pragma unroll
    for (int it = 0; it < 2; ++it)
#pragma unroll
        for (int j = 0; j < 4; ++j) m[it][j] = acc[it][j] * inv;

    float* outz = out + (size_t)B_ * N_ * T1_ + (size_t)bn * D_;
#pragma unroll
    for (int it = 0; it < 2; ++it) {
        int c4 = lane + 64 * it;
        if (c4 < D_ / 4) {
            float4 v;
            v.x = m[it][0]; v.y = m[it][1]; v.z = m[it][2]; v.w = m[it][3];
            *(float4*)(outz + c4 * 4) = v;
        }
    }

    float part[T1_] = {0, 0, 0, 0, 0, 0};
#pragma unroll
    for (int it = 0; it < 2; ++it) {
        int c4 = lane + 64 * it;
        if (c4 < D_ / 4) {
#pragma unroll
            for (int t = 0; t < T1_; ++t)
#pragma unroll
                for (int j = 0; j < 4; ++j)
                    part[t] += m[it][j] * Wpred[t * D_ + c4 * 4 + j];
        }
    }
#pragma unroll
    for (int t = 0; t < T1_; ++t) {
        float v = part[t];
        for (int off = 32; off; off >>= 1) v += __shfl_down(v, off);
        if (lane == 0)
            out[(size_t)bn * T1_ + t] = (cnt > 0) ? (v + bpred[t]) : 0.f;
    }
    if (lane == 0)
        out[(size_t)B_ * N_ * T1_ + (size_t)B_ * N_ * D_ + bn] =
            (cnt > 0) ? 1.f : 0.f;
}

// ======================= fallback (atomic) path kernels =====================
__global__ void k_zero(float* __restrict__ sums, int* __restrict__ counts) {
    int stride = gridDim.x * blockDim.x;
    int i0 = blockIdx.x * blockDim.x + threadIdx.x;
    for (int i = i0; i < B_ * N_ * D_; i += stride) sums[i] = 0.f;
    for (int i = i0; i < B_ * N_; i += stride) counts[i] = 0;
}

__global__ __launch_bounds__(128)
void k_level0_at(const float* __restrict__ feats, const int* __restrict__ seg,
                 const int* __restrict__ endi, unsigned short* __restrict__ z0,
                 float* __restrict__ sums) {
    int bk = blockIdx.x;
    int b = bk >> 12;
    int k = bk & (K_ - 1);
    int sidx = (b * L_ + 0) * K_ + k;
    int n = seg[sidx];
    int e = endi[sidx];
    const float* src = feats + ((size_t)b * N_ + n) * D_;
    unsigned short* dst = z0 + ((size_t)b * K_ + k) * D_;
    float* sm = sums + ((size_t)b * N_ + n) * D_;
    int t = threadIdx.x;
    if (t < D_ / 4) {
        float4 v = *(const float4*)(src + t * 4);
        ushort4 o;
        o.x = f2bf(v.x); o.y = f2bf(v.y); o.z = f2bf(v.z); o.w = f2bf(v.w);
        *(ushort4*)(dst + t * 4) = o;
        if (e) {
            atomicAdd(&sm[t * 4 + 0], v.x);
            atomicAdd(&sm[t * 4 + 1], v.y);
            atomicAdd(&sm[t * 4 + 2], v.z);
            atomicAdd(&sm[t * 4 + 3], v.w);
        }
    }
}

__global__ __launch_bounds__(256)
void k_level_mfma_at(const float* __restrict__ feats,
                     const float* __restrict__ attn,
                     const int* __restrict__ seg, const int* __restrict__ parent,
                     const int* __restrict__ endi,
                     const unsigned short* __restrict__ wb,
                     const unsigned short* __restrict__ zprev,
                     unsigned short* __restrict__ zcur,
                     float* __restrict__ sums, int l, int storez) {
    __shared__ int par_s[BM], seg_s[BM], end_s[BM];
    __shared__ float alpha_s[BM];
    int b = blockIdx.z;
    int k0 = blockIdx.x * BM;
    int d0 = blockIdx.y * BN;
    int tid = threadIdx.x;
    if (tid < BM) {
        int base = (b * L_ + l) * K_;
        int p = parent[base + k0 + tid];
        int sk = seg[base + k0 + tid];
        int ps = seg[base - K_ + p];
        par_s[tid] = p; seg_s[tid] = sk;
        end_s[tid] = endi[base + k0 + tid];
        alpha_s[tid] = attn[((size_t)b * N_ + ps) * N_ + sk];
    }
    __syncthreads();
    int wave = tid >> 6, lane = tid & 63;
    int wr0 = (wave >> 1) * 32, wc0 = (wave & 1) * 48;
    int laneRow = lane & 15, laneK = (lane >> 4) * 8;
    const unsigned short* zb = zprev + (size_t)b * K_ * D_;
    const unsigned short* arow[2];
#pragma unroll
    for (int mi = 0; mi < 2; ++mi)
        arow[mi] = zb + (size_t)par_s[wr0 + mi * 16 + laneRow] * D_ + laneK;
    const unsigned short* brow[3];
#pragma unroll
    for (int ni = 0; ni < 3; ++ni)
        brow[ni] = wb + (size_t)(d0 + wc0 + ni * 16 + laneRow) * D_ + laneK;
    f32x4 acc[2][3];
#pragma unroll
    for (int mi = 0; mi < 2; ++mi)
#pragma unroll
        for (int ni = 0; ni < 3; ++ni) acc[mi][ni] = (f32x4)0.f;
    bf16x8 af[2], bfr[3];
#pragma unroll
    for (int mi = 0; mi < 2; ++mi) af[mi] = *(const bf16x8*)(arow[mi]);
#pragma unroll
    for (int ni = 0; ni < 3; ++ni) bfr[ni] = *(const bf16x8*)(brow[ni]);
#pragma unroll
    for (int e0 = 0; e0 < D_; e0 += 32) {
        bf16x8 an[2], bn[3];
        if (e0 + 32 < D_) {
#pragma unroll
            for (int mi = 0; mi < 2; ++mi) an[mi] = *(const bf16x8*)(arow[mi] + e0 + 32);
#pragma unroll
            for (int ni = 0; ni < 3; ++ni) bn[ni] = *(const bf16x8*)(brow[ni] + e0 + 32);
        }
#pragma unroll
        for (int mi = 0; mi < 2; ++mi)
#pragma unroll
            for (int ni = 0; ni < 3; ++ni)
                acc[mi][ni] = __builtin_amdgcn_mfma_f32_16x16x32_bf16(
                    af[mi], bfr[ni], acc[mi][ni], 0, 0, 0);
        if (e0 + 32 < D_) {
#pragma unroll
            for (int mi = 0; mi < 2; ++mi) af[mi] = an[mi];
#pragma unroll
            for (int ni = 0; ni < 3; ++ni) bfr[ni] = bn[ni];
        }
    }
#pragma unroll
    for (int mi = 0; mi < 2; ++mi) {
#pragma unroll
        for (int j = 0; j < 4; ++j) {
            int rl = wr0 + mi * 16 + (lane >> 4) * 4 + j;
            int k = k0 + rl;
            float al = alpha_s[rl];
            int sk = seg_s[rl];
            int en = end_s[rl];
            const float* hrow = feats + ((size_t)b * N_ + sk) * D_;
            unsigned short* zrow = zcur + ((size_t)b * K_ + k) * D_;
            float* srow = sums + ((size_t)b * N_ + sk) * D_;
#pragma unroll
            for (int ni = 0; ni < 3; ++ni) {
                int c = d0 + wc0 + ni * 16 + (lane & 15);
                float v = al * acc[mi][ni][j] + hrow[c];
                if (storez) zrow[c] = f2bf(v);
                if (en) atomicAdd(&srow[c], v);
            }
        }
    }
}

__global__ __launch_bounds__(64)
void k_final_at(const float* __restrict__ sums, const int* __restrict__ counts,
                const float* __restrict__ Wpred, const float* __restrict__ bpred,
                float* __restrict__ out) {
    int bn = blockIdx.x;
    int cnt = counts[bn];
    float inv = 1.f / (float)(cnt > 1 ? cnt : 1);
    int lane = threadIdx.x;
    const float* srow = sums + (size_t)bn * D_;
    float* zout = out + (size_t)B_ * N_ * T1_ + (size_t)bn * D_;
    float part[T1_] = {0, 0, 0, 0, 0, 0};
    for (int d = lane; d < D_; d += 64) {
        float mval = srow[d] * inv;
        zout[d] = mval;
#pragma unroll
        for (int t = 0; t < T1_; ++t) part[t] += mval * Wpred[t * D_ + d];
    }
#pragma unroll
    for (int t = 0; t < T1_; ++t) {
        float v = part[t];
        for (int off = 32; off; off >>= 1) v += __shfl_down(v, off);
        if (lane == 0)
            out[(size_t)bn * T1_ + t] = (cnt > 0) ? (v + bpred[t]) : 0.f;
    }
    if (lane == 0)
        out[(size_t)B_ * N_ * T1_ + (size_t)B_ * N_ * D_ + bn] =
            (cnt > 0) ? 1.f : 0.f;
}

// ===========================================================================
extern "C" void kernel_launch(void* const* d_in, const int* in_sizes, int n_in,
                              void* d_out, int out_size, void* d_ws,
                              size_t ws_size, hipStream_t stream) {
    const float* feats = (const float*)d_in[0];
    const float* attn  = (const float*)d_in[1];
    const int*   seg   = (const int*)d_in[2];
    const int*   par   = (const int*)d_in[3];
    const unsigned char* isend_raw = (const unsigned char*)d_in[4];
    const float* Wproj = (const float*)d_in[5];
    const float* Wpred = (const float*)d_in[6];
    const float* bpred = (const float*)d_in[7];

    char* p = (char*)d_ws;
    auto carve = [&p](size_t bytes) -> char* {
        char* r = p;
        p += (bytes + 255) & ~(size_t)255;
        return r;
    };

    // gather-path workspace
    size_t need = 0;
    {
        size_t q = 0;
        auto sz = [&q](size_t b) { q += (b + 255) & ~(size_t)255; };
        sz(B_ * N_ * 4);                    // counts
        sz(B_ * N_ * 4);                    // cursor
        sz((B_ * N_ + 1) * 4);              // offsets
        sz((size_t)B_ * L_ * K_ * 4);       // endi
        sz(16);                             // flag
        sz((size_t)B_ * L_ * K_ * 4);       // nodelist (worst case all end)
        sz((size_t)B_ * N_ * D_ * 2);       // featsbf
        sz((size_t)D_ * D_ * 2);            // wbf
        sz((size_t)(L_ - 1) * B_ * K_ * D_ * 2);  // zall: 7 slabs
        need = q;
    }

    if (ws_size >= need) {
        int* counts = (int*)carve(B_ * N_ * 4);
        int* cursor = (int*)carve(B_ * N_ * 4);
        int* offsets = (int*)carve((B_ * N_ + 1) * 4);
        int* endi = (int*)carve((size_t)B_ * L_ * K_ * 4);
        int* flag = (int*)carve(16);
        int* nodelist = (int*)carve((size_t)B_ * L_ * K_ * 4);
        unsigned short* featsbf = (unsigned short*)carve((size_t)B_ * N_ * D_ * 2);
        unsigned short* wbf = (unsigned short*)carve((size_t)D_ * D_ * 2);
        unsigned short* zall =
            (unsigned short*)carve((size_t)(L_ - 1) * B_ * K_ * D_ * 2);

        k_flag<<<1, 256, 0, stream>>>(isend_raw, flag);
        k_zero_idx<<<(B_ * N_ + 255) / 256, 256, 0, stream>>>(counts, cursor);
        k_wconv<<<(D_ * D_ + 255) / 256, 256, 0, stream>>>(Wproj, wbf);
        k_feats2bf<<<(B_ * N_ * D_ / 4 + 255) / 256, 256, 0, stream>>>(feats,
                                                                       featsbf);
        k_endcounts<<<(B_ * L_ * K_ + 255) / 256, 256, 0, stream>>>(
            isend_raw, flag, seg, endi, counts);
        k_scan<<<1, 256, 0, stream>>>(counts, offsets);
        k_build<<<(B_ * L_ * K_ + 255) / 256, 256, 0, stream>>>(
            endi, seg, offsets, cursor, nodelist);

        for (int l = 1; l < L_; ++l) {
            const unsigned short* zp =
                (l == 1) ? featsbf : zall + (size_t)(l - 2) * B_ * K_ * D_;
            unsigned short* zc = zall + (size_t)(l - 1) * B_ * K_ * D_;
            k_level_gemm<<<768, 512, 0, stream>>>(
                attn, seg, par, featsbf, wbf, zp, zc, l,
                (l == 1) ? N_ : K_, (l == 1) ? 1 : 0);
        }

        k_final_gather<<<B_ * N_, 64, 0, stream>>>(
            featsbf, zall, offsets, nodelist, Wpred, bpred, (float*)d_out);
    } else {
        // fallback: round-3 atomic path
        float* sums = (float*)carve((size_t)B_ * N_ * D_ * 4);
        int* counts = (int*)carve(B_ * N_ * 4);
        int* endi = (int*)carve((size_t)B_ * L_ * K_ * 4);
        int* flag = (int*)carve(16);
        unsigned short* z0bf = (unsigned short*)carve((size_t)B_ * K_ * D_ * 2);
        unsigned short* z1bf = (unsigned short*)carve((size_t)B_ * K_ * D_ * 2);
        unsigned short* wbf = (unsigned short*)carve((size_t)D_ * D_ * 2);

        k_flag<<<1, 256, 0, stream>>>(isend_raw, flag);
        k_zero<<<1024, 256, 0, stream>>>(sums, counts);
        k_wconv<<<(D_ * D_ + 255) / 256, 256, 0, stream>>>(Wproj, wbf);
        k_endcounts<<<(B_ * L_ * K_ + 255) / 256, 256, 0, stream>>>(
            isend_raw, flag, seg, endi, counts);
        k_level0_at<<<B_ * K_, 128, 0, stream>>>(feats, seg, endi, z0bf, sums);
        unsigned short* zp = z0bf;
        unsigned short* zc = z1bf;
        for (int l = 1; l < L_; ++l) {
            k_level_mfma_at<<<dim3(K_ / BM, D_ / BN, B_), 256, 0, stream>>>(
                feats, attn, seg, par, endi, wbf, zp, zc, sums, l,
                (l < L_ - 1) ? 1 : 0);
            unsigned short* t = zp; zp = zc; zc = t;
        }
        k_final_at<<<B_ * N_, 64, 0, stream>>>(sums, counts, Wpred, bpred,
                                               (float*)d_out);
    }
}

// Round 10
// 324.534 us; speedup vs baseline: 1.0689x; 1.0066x over previous
//
#include <hip/hip_runtime.h>

// Problem constants
#define B_ 8
#define N_ 2000
#define D_ 480          // NH*C = 30*16
#define L_ 8
#define K_ 4096
#define T1_ 6

#define BM 64
#define BN 96

typedef __attribute__((ext_vector_type(4))) float f32x4;
typedef __attribute__((ext_vector_type(8))) short bf16x8;

__device__ __forceinline__ unsigned short f2bf(float f) {
    unsigned int u = __builtin_bit_cast(unsigned int, f);
    u += 0x7fffu + ((u >> 16) & 1u);   // RNE
    return (unsigned short)(u >> 16);
}
__device__ __forceinline__ float bf2f(unsigned short u) {
    return __builtin_bit_cast(float, ((unsigned int)u) << 16);
}

// Raw barrier WITHOUT the vmcnt(0) drain __syncthreads() implies.
// lgkmcnt(0) gives LDS-write visibility; in-flight global loads survive.
__device__ __forceinline__ void barrier_nodrain() {
    asm volatile("s_waitcnt lgkmcnt(0)" ::: "memory");
    __builtin_amdgcn_s_barrier();
}

// ---------------------------------------------------------------------------
// is_end storage sniff: 1 => 1-byte bool, 0 => int32 (bytes %4!=0 all zero).
__global__ __launch_bounds__(256)
void k_flag(const unsigned char* __restrict__ raw, int* flag) {
    int t = threadIdx.x;
    if (t == 0) *flag = 0;
    __syncthreads();
    int any = 0;
    for (int i = t; i < 4096; i += 256) {
        if ((i & 3) != 0 && raw[i] != 0) any = 1;
    }
    if (__any(any) && (t & 63) == 0) atomicOr(flag, 1);
}

__global__ void k_wconv(const float* __restrict__ w,
                        unsigned short* __restrict__ wbf) {
    int i = blockIdx.x * blockDim.x + threadIdx.x;
    if (i < D_ * D_) wbf[i] = f2bf(w[i]);
}

__global__ void k_feats2bf(const float* __restrict__ f,
                           unsigned short* __restrict__ o) {
    int i = blockIdx.x * blockDim.x + threadIdx.x;   // over float4s
    if (i < B_ * N_ * D_ / 4) {
        float4 v = ((const float4*)f)[i];
        ushort4 u;
        u.x = f2bf(v.x); u.y = f2bf(v.y); u.z = f2bf(v.z); u.w = f2bf(v.w);
        ((ushort4*)o)[i] = u;
    }
}

__global__ void k_zero_idx(int* __restrict__ counts, int* __restrict__ cursor) {
    int i = blockIdx.x * blockDim.x + threadIdx.x;
    if (i < B_ * N_) { counts[i] = 0; cursor[i] = 0; }
}

__global__ void k_endcounts(const unsigned char* __restrict__ raw,
                            const int* __restrict__ flag,
                            const int* __restrict__ seg,
                            int* __restrict__ endi, int* __restrict__ counts) {
    int i = blockIdx.x * blockDim.x + threadIdx.x;
    if (i >= B_ * L_ * K_) return;
    int e = (*flag) ? (int)raw[i] : ((const int*)raw)[i];
    e = (e != 0) ? 1 : 0;
    endi[i] = e;
    if (e) {
        int b = i / (L_ * K_);
        atomicAdd(&counts[b * N_ + seg[i]], 1);
    }
}

// offsets = exclusive prefix sum of counts (B*N entries -> B*N+1 offsets)
__global__ __launch_bounds__(256)
void k_scan(const int* __restrict__ counts, int* __restrict__ offsets) {
    __shared__ int part[256];
    const int CH = 63;                       // 256*63 = 16128 >= 16000
    int t = threadIdx.x;
    int s = 0;
    for (int j = 0; j < CH; ++j) {
        int i = t * CH + j;
        if (i < B_ * N_) s += counts[i];
    }
    part[t] = s;
    __syncthreads();
    if (t == 0) {
        int run = 0;
        for (int i = 0; i < 256; ++i) { int v = part[i]; part[i] = run; run += v; }
    }
    __syncthreads();
    int run = part[t];
    for (int j = 0; j < CH; ++j) {
        int i = t * CH + j;
        if (i < B_ * N_) { offsets[i] = run; run += counts[i]; }
    }
    if (t == 255) offsets[B_ * N_] = run;
}

// nodelist grouped by (b,n): entry = l*K + k  (l<8, K=4096 -> (l<<12)|k)
__global__ void k_build(const int* __restrict__ endi,
                        const int* __restrict__ seg,
                        const int* __restrict__ offsets,
                        int* __restrict__ cursor, int* __restrict__ nodelist) {
    int i = blockIdx.x * blockDim.x + threadIdx.x;   // over B*L*K
    if (i >= B_ * L_ * K_) return;
    if (!endi[i]) return;
    int b = i / (L_ * K_);
    int lk = i - b * (L_ * K_);                      // l*K + k
    int n = seg[i];
    int pos = atomicAdd(&cursor[b * N_ + n], 1);
    nodelist[offsets[b * N_ + n] + pos] = lk;
}

// ---------------------------------------------------------------------------
// Level l>=1: depth-2 pipelined LDS GEMM, triple-buffered, NO-DRAIN barriers.
// Z_l = diag(alpha)*(Z_{l-1}[gidx] @ W^T) + H_l.
// Tile 128x160, BK=32, 512 threads = 8 waves (4M x 2N), wave = 32x80 = 2x5
// frags of 16x16x32 bf16.  Slice s+2 issued at step s, LDS-written at s+1.
// KEY FIX vs r9: __syncthreads() compiles to s_waitcnt vmcnt(0) before
// s_barrier -> drained the prefetch queue every step (m97 barrier-drain).
// barrier_nodrain() keeps loads in flight; compiler inserts counted vmcnt
// only before each dependent ds_write.  1 barrier/step is WAR-safe with
// triple buffer (buffer written at s last read at s-2).
__global__ __launch_bounds__(512, 4)
void k_level_gemm(const float* __restrict__ attn,
                  const int* __restrict__ seg, const int* __restrict__ parent,
                  const unsigned short* __restrict__ featsbf,
                  const unsigned short* __restrict__ wb,
                  const unsigned short* __restrict__ zprev,
                  unsigned short* __restrict__ zcur,
                  int l, int prevRows, int useps) {
    __shared__ unsigned short As[3][128 * 40];   // 80B/row stride
    __shared__ unsigned short Bs[3][160 * 40];
    __shared__ int gidx_s[128], seg_s[128];
    __shared__ float alpha_s[128];

    int tid = threadIdx.x;
    int id = blockIdx.x;                 // 768 = 8 xcds x 96
    int b = id & 7;                      // batch == XCD chunk
    int within = id >> 3;                // 0..95
    int mb = within / 3, nb = within - mb * 3;
    int k0 = mb * 128, d0 = nb * 160;

    if (tid < 128) {
        int base = (b * L_ + l) * K_;
        int p = parent[base + k0 + tid];
        int sk = seg[base + k0 + tid];
        int ps = seg[base - K_ + p];
        gidx_s[tid] = useps ? ps : p;
        seg_s[tid] = sk;
        alpha_s[tid] = attn[((size_t)b * N_ + ps) * N_ + sk];
    }
    barrier_nodrain();

    const unsigned short* zb = zprev + (size_t)b * prevRows * D_;

    // staging: 16B chunks. A: 128 rows x 4 = 512 = 1/thread.
    // B: 160 rows x 4 = 640 = 1/thread + extra for tid<128.
    int ar = tid >> 2, ao = (tid & 3) * 8;   // ao in shorts
    const unsigned short* asrc = zb + (size_t)gidx_s[ar] * D_ + ao;
    int aw = ar * 40 + ao;
    const unsigned short* bsrc0 = wb + (size_t)(d0 + ar) * D_ + ao;
    int bw0 = ar * 40 + ao;
    int br1 = 128 + (tid >> 2);
    const unsigned short* bsrc1 = wb + (size_t)(d0 + (br1 < 160 ? br1 : 159)) * D_ + ao;
    int bw1 = br1 * 40 + ao;
    bool hasB1 = (tid < 128);

    // fragment base offsets (shorts)
    int wave = tid >> 6, lane = tid & 63;
    int waveM = wave >> 1, waveN = wave & 1;  // 4M x 2N
    int lr = lane & 15, kg = lane >> 4;
    int afb[2], bfb[5];
#pragma unroll
    for (int fm = 0; fm < 2; ++fm)
        afb[fm] = (waveM * 32 + fm * 16 + lr) * 40 + kg * 8;
#pragma unroll
    for (int fn = 0; fn < 5; ++fn)
        bfb[fn] = (waveN * 80 + fn * 16 + lr) * 40 + kg * 8;

    f32x4 acc[2][5];
#pragma unroll
    for (int fm = 0; fm < 2; ++fm)
#pragma unroll
        for (int fn = 0; fn < 5; ++fn) acc[fm][fn] = (f32x4)0.f;

    // 2-deep staging registers: slot = slice & 1
    f32x4 ra[2], rb0[2], rb1[2];

    // prologue: slice0 -> LDS[0]; slice1 -> reg slot1; slice2 -> reg slot0
    {
        f32x4 a0 = *(const f32x4*)(asrc);
        f32x4 b00 = *(const f32x4*)(bsrc0);
        f32x4 b10; if (hasB1) b10 = *(const f32x4*)(bsrc1);
        ra[1]  = *(const f32x4*)(asrc + 32);
        rb0[1] = *(const f32x4*)(bsrc0 + 32);
        if (hasB1) rb1[1] = *(const f32x4*)(bsrc1 + 32);
        ra[0]  = *(const f32x4*)(asrc + 64);
        rb0[0] = *(const f32x4*)(bsrc0 + 64);
        if (hasB1) rb1[0] = *(const f32x4*)(bsrc1 + 64);
        *(f32x4*)&As[0][aw] = a0;
        *(f32x4*)&Bs[0][bw0] = b00;
        if (hasB1) *(f32x4*)&Bs[0][bw1] = b10;
    }
    barrier_nodrain();

#pragma unroll
    for (int s = 0; s < 15; ++s) {
        // phase 1: issue slice s+2 (slices 1,2 issued in prologue)
        if (s >= 1 && s + 2 <= 14) {
            int off = (s + 2) * 32;
            int sl = s & 1;                    // (s+2)&1 == s&1
            ra[sl] = *(const f32x4*)(asrc + off);
            rb0[sl] = *(const f32x4*)(bsrc0 + off);
            if (hasB1) rb1[sl] = *(const f32x4*)(bsrc1 + off);
        }
        // phase 2: fragments + MFMA from buffer s%3
        int cur = s % 3;
        bf16x8 af[2], bfr[5];
#pragma unroll
        for (int fm = 0; fm < 2; ++fm)
            af[fm] = *(const bf16x8*)&As[cur][afb[fm]];
#pragma unroll
        for (int fn = 0; fn < 5; ++fn)
            bfr[fn] = *(const bf16x8*)&Bs[cur][bfb[fn]];
#pragma unroll
        for (int fm = 0; fm < 2; ++fm)
#pragma unroll
            for (int fn = 0; fn < 5; ++fn)
                acc[fm][fn] = __builtin_amdgcn_mfma_f32_16x16x32_bf16(
                    af[fm], bfr[fn], acc[fm][fn], 0, 0, 0);
        // phase 3: write slice s+1 (issued 2 steps ago) into buffer (s+1)%3
        if (s <= 13) {
            int sl = (s + 1) & 1;
            int buf = (s + 1) % 3;
            *(f32x4*)&As[buf][aw] = ra[sl];
            *(f32x4*)&Bs[buf][bw0] = rb0[sl];
            if (hasB1) *(f32x4*)&Bs[buf][bw1] = rb1[sl];
        }
        barrier_nodrain();
    }

    // epilogue: C layout col=lane&15, row=(lane>>4)*4+j
#pragma unroll
    for (int fm = 0; fm < 2; ++fm) {
#pragma unroll
        for (int j = 0; j < 4; ++j) {
            int rl = waveM * 32 + fm * 16 + kg * 4 + j;
            float al = alpha_s[rl];
            int sk = seg_s[rl];
            const unsigned short* hrow = featsbf + ((size_t)b * N_ + sk) * D_;
            unsigned short* zrow = zcur + ((size_t)b * K_ + k0 + rl) * D_;
#pragma unroll
            for (int fn = 0; fn < 5; ++fn) {
                int c = d0 + waveN * 80 + fn * 16 + lr;
                zrow[c] = f2bf(al * acc[fm][fn][j] + bf2f(hrow[c]));
            }
        }
    }
}

// Fused gather-reduce + mean + predictor + mask. One wave per (b,n).
__global__ __launch_bounds__(64)
void k_final_gather(const unsigned short* __restrict__ featsbf,
                    const unsigned short* __restrict__ zall,
                    const int* __restrict__ offsets,
                    const int* __restrict__ nodelist,
                    const float* __restrict__ Wpred,
                    const float* __restrict__ bpred, float* __restrict__ out) {
    int bn = blockIdx.x;
    int b = bn / N_;
    int s0 = offsets[bn], s1 = offsets[bn + 1];
    int cnt = s1 - s0;
    int lane = threadIdx.x;

    float acc[2][4] = {{0, 0, 0, 0}, {0, 0, 0, 0}};
    const unsigned short* ownrow = featsbf + (size_t)bn * D_;

    for (int s = s0; s < s1; ++s) {
        int e = nodelist[s];
        int l = e >> 12, k = e & (K_ - 1);
        const unsigned short* row =
            (l == 0) ? ownrow
                     : zall + (((size_t)(l - 1) * B_ + b) * K_ + k) * D_;
#pragma unroll
        for (int it = 0; it < 2; ++it) {
            int c4 = lane + 64 * it;
            if (c4 < D_ / 4) {
                ushort4 u = *(const ushort4*)(row + c4 * 4);
                acc[it][0] += bf2f(u.x);
                acc[it][1] += bf2f(u.y);
                acc[it][2] += bf2f(u.z);
                acc[it][3] += bf2f(u.w);
            }
        }
    }

    float inv = 1.f / (float)(cnt > 1 ? cnt : 1);
    float m[2][4];
#pragma unroll
    for (int it = 0; it < 2; ++it)
#pragma unroll
        for (int j = 0; j < 4; ++j) m[it][j] = acc[it][j] * inv;

    float* outz = out + (size_t)B_ * N_ * T1_ + (size_t)bn * D_;
#pragma unroll
    for (int it = 0; it < 2; ++it) {
        int c4 = lane + 64 * it;
        if (c4 < D_ / 4) {
            float4 v;
            v.x = m[it][0]; v.y = m[it][1]; v.z = m[it][2]; v.w = m[it][3];
            *(float4*)(outz + c4 * 4) = v;
        }
    }

    float part[T1_] = {0, 0, 0, 0, 0, 0};
#pragma unroll
    for (int it = 0; it < 2; ++it) {
        int c4 = lane + 64 * it;
        if (c4 < D_ / 4) {
#pragma unroll
            for (int t = 0; t < T1_; ++t)
#pragma unroll
                for (int j = 0; j < 4; ++j)
                    part[t] += m[it][j] * Wpred[t * D_ + c4 * 4 + j];
        }
    }
#pragma unroll
    for (int t = 0; t < T1_; ++t) {
        float v = part[t];
        for (int off = 32; off; off >>= 1) v += __shfl_down(v, off);
        if (lane == 0)
            out[(size_t)bn * T1_ + t] = (cnt > 0) ? (v + bpred[t]) : 0.f;
    }
    if (lane == 0)
        out[(size_t)B_ * N_ * T1_ + (size_t)B_ * N_ * D_ + bn] =
            (cnt > 0) ? 1.f : 0.f;
}

// ======================= fallback (atomic) path kernels =====================
__global__ void k_zero(float* __restrict__ sums, int* __restrict__ counts) {
    int stride = gridDim.x * blockDim.x;
    int i0 = blockIdx.x * blockDim.x + threadIdx.x;
    for (int i = i0; i < B_ * N_ * D_; i += stride) sums[i] = 0.f;
    for (int i = i0; i < B_ * N_; i += stride) counts[i] = 0;
}

__global__ __launch_bounds__(128)
void k_level0_at(const float* __restrict__ feats, const int* __restrict__ seg,
                 const int* __restrict__ endi, unsigned short* __restrict__ z0,
                 float* __restrict__ sums) {
    int bk = blockIdx.x;
    int b = bk >> 12;
    int k = bk & (K_ - 1);
    int sidx = (b * L_ + 0) * K_ + k;
    int n = seg[sidx];
    int e = endi[sidx];
    const float* src = feats + ((size_t)b * N_ + n) * D_;
    unsigned short* dst = z0 + ((size_t)b * K_ + k) * D_;
    float* sm = sums + ((size_t)b * N_ + n) * D_;
    int t = threadIdx.x;
    if (t < D_ / 4) {
        float4 v = *(const float4*)(src + t * 4);
        ushort4 o;
        o.x = f2bf(v.x); o.y = f2bf(v.y); o.z = f2bf(v.z); o.w = f2bf(v.w);
        *(ushort4*)(dst + t * 4) = o;
        if (e) {
            atomicAdd(&sm[t * 4 + 0], v.x);
            atomicAdd(&sm[t * 4 + 1], v.y);
            atomicAdd(&sm[t * 4 + 2], v.z);
            atomicAdd(&sm[t * 4 + 3], v.w);
        }
    }
}

__global__ __launch_bounds__(256)
void k_level_mfma_at(const float* __restrict__ feats,
                     const float* __restrict__ attn,
                     const int* __restrict__ seg, const int* __restrict__ parent,
                     const int* __restrict__ endi,
                     const unsigned short* __restrict__ wb,
                     const unsigned short* __restrict__ zprev,
                     unsigned short* __restrict__ zcur,
                     float* __restrict__ sums, int l, int storez) {
    __shared__ int par_s[BM], seg_s[BM], end_s[BM];
    __shared__ float alpha_s[BM];
    int b = blockIdx.z;
    int k0 = blockIdx.x * BM;
    int d0 = blockIdx.y * BN;
    int tid = threadIdx.x;
    if (tid < BM) {
        int base = (b * L_ + l) * K_;
        int p = parent[base + k0 + tid];
        int sk = seg[base + k0 + tid];
        int ps = seg[base - K_ + p];
        par_s[tid] = p; seg_s[tid] = sk;
        end_s[tid] = endi[base + k0 + tid];
        alpha_s[tid] = attn[((size_t)b * N_ + ps) * N_ + sk];
    }
    __syncthreads();
    int wave = tid >> 6, lane = tid & 63;
    int wr0 = (wave >> 1) * 32, wc0 = (wave & 1) * 48;
    int laneRow = lane & 15, laneK = (lane >> 4) * 8;
    const unsigned short* zb = zprev + (size_t)b * K_ * D_;
    const unsigned short* arow[2];
#pragma unroll
    for (int mi = 0; mi < 2; ++mi)
        arow[mi] = zb + (size_t)par_s[wr0 + mi * 16 + laneRow] * D_ + laneK;
    const unsigned short* brow[3];
#pragma unroll
    for (int ni = 0; ni < 3; ++ni)
        brow[ni] = wb + (size_t)(d0 + wc0 + ni * 16 + laneRow) * D_ + laneK;
    f32x4 acc[2][3];
#pragma unroll
    for (int mi = 0; mi < 2; ++mi)
#pragma unroll
        for (int ni = 0; ni < 3; ++ni) acc[mi][ni] = (f32x4)0.f;
    bf16x8 af[2], bfr[3];
#pragma unroll
    for (int mi = 0; mi < 2; ++mi) af[mi] = *(const bf16x8*)(arow[mi]);
#pragma unroll
    for (int ni = 0; ni < 3; ++ni) bfr[ni] = *(const bf16x8*)(brow[ni]);
#pragma unroll
    for (int e0 = 0; e0 < D_; e0 += 32) {
        bf16x8 an[2], bn[3];
        if (e0 + 32 < D_) {
#pragma unroll
            for (int mi = 0; mi < 2; ++mi) an[mi] = *(const bf16x8*)(arow[mi] + e0 + 32);
#pragma unroll
            for (int ni = 0; ni < 3; ++ni) bn[ni] = *(const bf16x8*)(brow[ni] + e0 + 32);
        }
#pragma unroll
        for (int mi = 0; mi < 2; ++mi)
#pragma unroll
            for (int ni = 0; ni < 3; ++ni)
                acc[mi][ni] = __builtin_amdgcn_mfma_f32_16x16x32_bf16(
                    af[mi], bfr[ni], acc[mi][ni], 0, 0, 0);
        if (e0 + 32 < D_) {
#pragma unroll
            for (int mi = 0; mi < 2; ++mi) af[mi] = an[mi];
#pragma unroll
            for (int ni = 0; ni < 3; ++ni) bfr[ni] = bn[ni];
        }
    }
#pragma unroll
    for (int mi = 0; mi < 2; ++mi) {
#pragma unroll
        for (int j = 0; j < 4; ++j) {
            int rl = wr0 + mi * 16 + (lane >> 4) * 4 + j;
            int k = k0 + rl;
            float al = alpha_s[rl];
            int sk = seg_s[rl];
            int en = end_s[rl];
            const float* hrow = feats + ((size_t)b * N_ + sk) * D_;
            unsigned short* zrow = zcur + ((size_t)b * K_ + k) * D_;
            float* srow = sums + ((size_t)b * N_ + sk) * D_;
#pragma unroll
            for (int ni = 0; ni < 3; ++ni) {
                int c = d0 + wc0 + ni * 16 + (lane & 15);
                float v = al * acc[mi][ni][j] + hrow[c];
                if (storez) zrow[c] = f2bf(v);
                if (en) atomicAdd(&srow[c], v);
            }
        }
    }
}

__global__ __launch_bounds__(64)
void k_final_at(const float* __restrict__ sums, const int* __restrict__ counts,
                const float* __restrict__ Wpred, const float* __restrict__ bpred,
                float* __restrict__ out) {
    int bn = blockIdx.x;
    int cnt = counts[bn];
    float inv = 1.f / (float)(cnt > 1 ? cnt : 1);
    int lane = threadIdx.x;
    const float* srow = sums + (size_t)bn * D_;
    float* zout = out + (size_t)B_ * N_ * T1_ + (size_t)bn * D_;
    float part[T1_] = {0, 0, 0, 0, 0, 0};
    for (int d = lane; d < D_; d += 64) {
        float mval = srow[d] * inv;
        zout[d] = mval;
#pragma unroll
        for (int t = 0; t < T1_; ++t) part[t] += mval * Wpred[t * D_ + d];
    }
#pragma unroll
    for (int t = 0; t < T1_; ++t) {
        float v = part[t];
        for (int off = 32; off; off >>= 1) v += __shfl_down(v, off);
        if (lane == 0)
            out[(size_t)bn * T1_ + t] = (cnt > 0) ? (v + bpred[t]) : 0.f;
    }
    if (lane == 0)
        out[(size_t)B_ * N_ * T1_ + (size_t)B_ * N_ * D_ + bn] =
            (cnt > 0) ? 1.f : 0.f;
}

// ===========================================================================
extern "C" void kernel_launch(void* const* d_in, const int* in_sizes, int n_in,
                              void* d_out, int out_size, void* d_ws,
                              size_t ws_size, hipStream_t stream) {
    const float* feats = (const float*)d_in[0];
    const float* attn  = (const float*)d_in[1];
    const int*   seg   = (const int*)d_in[2];
    const int*   par   = (const int*)d_in[3];
    const unsigned char* isend_raw = (const unsigned char*)d_in[4];
    const float* Wproj = (const float*)d_in[5];
    const float* Wpred = (const float*)d_in[6];
    const float* bpred = (const float*)d_in[7];

    char* p = (char*)d_ws;
    auto carve = [&p](size_t bytes) -> char* {
        char* r = p;
        p += (bytes + 255) & ~(size_t)255;
        return r;
    };

    // gather-path workspace
    size_t need = 0;
    {
        size_t q = 0;
        auto sz = [&q](size_t b) { q += (b + 255) & ~(size_t)255; };
        sz(B_ * N_ * 4);                    // counts
        sz(B_ * N_ * 4);                    // cursor
        sz((B_ * N_ + 1) * 4);              // offsets
        sz((size_t)B_ * L_ * K_ * 4);       // endi
        sz(16);                             // flag
        sz((size_t)B_ * L_ * K_ * 4);       // nodelist (worst case all end)
        sz((size_t)B_ * N_ * D_ * 2);       // featsbf
        sz((size_t)D_ * D_ * 2);            // wbf
        sz((size_t)(L_ - 1) * B_ * K_ * D_ * 2);  // zall: 7 slabs
        need = q;
    }

    if (ws_size >= need) {
        int* counts = (int*)carve(B_ * N_ * 4);
        int* cursor = (int*)carve(B_ * N_ * 4);
        int* offsets = (int*)carve((B_ * N_ + 1) * 4);
        int* endi = (int*)carve((size_t)B_ * L_ * K_ * 4);
        int* flag = (int*)carve(16);
        int* nodelist = (int*)carve((size_t)B_ * L_ * K_ * 4);
        unsigned short* featsbf = (unsigned short*)carve((size_t)B_ * N_ * D_ * 2);
        unsigned short* wbf = (unsigned short*)carve((size_t)D_ * D_ * 2);
        unsigned short* zall =
            (unsigned short*)carve((size_t)(L_ - 1) * B_ * K_ * D_ * 2);

        k_flag<<<1, 256, 0, stream>>>(isend_raw, flag);
        k_zero_idx<<<(B_ * N_ + 255) / 256, 256, 0, stream>>>(counts, cursor);
        k_wconv<<<(D_ * D_ + 255) / 256, 256, 0, stream>>>(Wproj, wbf);
        k_feats2bf<<<(B_ * N_ * D_ / 4 + 255) / 256, 256, 0, stream>>>(feats,
                                                                       featsbf);
        k_endcounts<<<(B_ * L_ * K_ + 255) / 256, 256, 0, stream>>>(
            isend_raw, flag, seg, endi, counts);
        k_scan<<<1, 256, 0, stream>>>(counts, offsets);
        k_build<<<(B_ * L_ * K_ + 255) / 256, 256, 0, stream>>>(
            endi, seg, offsets, cursor, nodelist);

        for (int l = 1; l < L_; ++l) {
            const unsigned short* zp =
                (l == 1) ? featsbf : zall + (size_t)(l - 2) * B_ * K_ * D_;
            unsigned short* zc = zall + (size_t)(l - 1) * B_ * K_ * D_;
            k_level_gemm<<<768, 512, 0, stream>>>(
                attn, seg, par, featsbf, wbf, zp, zc, l,
                (l == 1) ? N_ : K_, (l == 1) ? 1 : 0);
        }

        k_final_gather<<<B_ * N_, 64, 0, stream>>>(
            featsbf, zall, offsets, nodelist, Wpred, bpred, (float*)d_out);
    } else {
        // fallback: round-3 atomic path
        float* sums = (float*)carve((size_t)B_ * N_ * D_ * 4);
        int* counts = (int*)carve(B_ * N_ * 4);
        int* endi = (int*)carve((size_t)B_ * L_ * K_ * 4);
        int* flag = (int*)carve(16);
        unsigned short* z0bf = (unsigned short*)carve((size_t)B_ * K_ * D_ * 2);
        unsigned short* z1bf = (unsigned short*)carve((size_t)B_ * K_ * D_ * 2);
        unsigned short* wbf = (unsigned short*)carve((size_t)D_ * D_ * 2);

        k_flag<<<1, 256, 0, stream>>>(isend_raw, flag);
        k_zero<<<1024, 256, 0, stream>>>(sums, counts);
        k_wconv<<<(D_ * D_ + 255) / 256, 256, 0, stream>>>(Wproj, wbf);
        k_endcounts<<<(B_ * L_ * K_ + 255) / 256, 256, 0, stream>>>(
            isend_raw, flag, seg, endi, counts);
        k_level0_at<<<B_ * K_, 128, 0, stream>>>(feats, seg, endi, z0bf, sums);
        unsigned short* zp = z0bf;
        unsigned short* zc = z1bf;
        for (int l = 1; l < L_; ++l) {
            k_level_mfma_at<<<dim3(K_ / BM, D_ / BN, B_), 256, 0, stream>>>(
                feats, attn, seg, par, endi, wbf, zp, zc, sums, l,
                (l < L_ - 1) ? 1 : 0);
            unsigned short* t = zp; zp = zc; zc = t;
        }
        k_final_at<<<B_ * N_, 64, 0, stream>>>(sums, counts, Wpred, bpred,
                                               (float*)d_out);
    }
}